// Round 9
// baseline (237.970 us; speedup 1.0000x reference)
//
#include <hip/hip_runtime.h>
#include <hip/hip_bf16.h>

#define H 8
#define DM 512
#define DK 64
#define LSEQ 4096
#define NB 2
#define NSPLIT 4
#define KSPAN (LSEQ / NSPLIT)   // keys per split = 1024
#define NIT (KSPAN / 64)        // 16 k-tiles per block

// 0.125 (1/sqrt(DK)) * log2(e): folded into Q so softmax uses exp2 directly
#define QSCALE 0.18033688011112042f

typedef float f32x4 __attribute__((ext_vector_type(4)));
typedef __bf16 bf16x8 __attribute__((ext_vector_type(8)));
typedef __bf16 bf16x2 __attribute__((ext_vector_type(2)));
typedef unsigned short u16;

__device__ __forceinline__ u16 f2bf(float f) {
    union { float f; unsigned u; } v{f};
    return (u16)((v.u + 0x8000u) >> 16);
}

__device__ __forceinline__ unsigned pkbf(float a, float b) {
#if __has_builtin(__builtin_amdgcn_cvt_pk_bf16_f32)
    union { bf16x2 v; unsigned u; } x;
    x.v = __builtin_amdgcn_cvt_pk_bf16_f32(a, b);
    return x.u;
#else
    union { float f; unsigned u; } x{a}, y{b};
    return ((x.u + 0x8000u) >> 16) | ((y.u + 0x8000u) & 0xffff0000u);
#endif
}

__device__ __forceinline__ ushort4 cvt4(float4 a) {
    union { ushort4 s; uint2 u; } o;
    o.u.x = pkbf(a.x, a.y);
    o.u.y = pkbf(a.z, a.w);
    return o.s;
}

__device__ __forceinline__ float2 ubf2(unsigned u) {
    union { float f; unsigned v; } a, b;
    a.v = u << 16;
    b.v = u & 0xffff0000u;
    return make_float2(a.f, b.f);
}

__device__ __forceinline__ float fexp2(float x) {
#if __has_builtin(__builtin_amdgcn_exp2f)
    return __builtin_amdgcn_exp2f(x);
#else
    return exp2f(x);
#endif
}

__device__ __forceinline__ f32x4 mfma32(bf16x8 a, bf16x8 b, f32x4 c) {
    return __builtin_amdgcn_mfma_f32_16x16x32_bf16(a, b, c, 0, 0, 0);
}

// ---------------------------------------------------------------------------
// r17: one-shot fp32 -> bf16 conversion of the 4 weight matrices AND the 3
// activation tensors (X re-read 4x by proj_qkv's n-blocks: bf16 halves that
// traffic and deletes all staging-side cvt VALU). Same pkbf RNE conversion
// as the old inline path -> bit-identical numerics. y<4: W (128 blocks);
// y>=4: X (2048 blocks).
// ---------------------------------------------------------------------------
__launch_bounds__(256, 8)
__global__ void cvt_all(const float* __restrict__ W0, const float* __restrict__ W1,
                        const float* __restrict__ W2, const float* __restrict__ W3,
                        const float* __restrict__ X0, const float* __restrict__ X1,
                        const float* __restrict__ X2,
                        u16* __restrict__ wout, u16* __restrict__ xout)
{
    const int y = blockIdx.y;
    const float* src;
    u16* dst;
    int nblk;
    if (y < 4) {
        src = (y == 0) ? W0 : (y == 1) ? W1 : (y == 2) ? W2 : W3;
        dst = wout + (size_t)y * DM * DM;
        nblk = (DM * DM) / (256 * 8);              // 128
    } else {
        src = (y == 4) ? X0 : (y == 5) ? X1 : X2;
        dst = xout + (size_t)(y - 4) * ((size_t)NB * LSEQ * DM);
        nblk = ((size_t)NB * LSEQ * DM) / (256 * 8); // 2048
    }
    if ((int)blockIdx.x >= nblk) return;
    size_t base = ((size_t)blockIdx.x * 256 + threadIdx.x) * 8;
    float4 a = *(const float4*)(src + base);
    float4 b = *(const float4*)(src + base + 4);
    *(ushort4*)(dst + base)     = cvt4(a);
    *(ushort4*)(dst + base + 4) = cvt4(b);
}

// ---------------------------------------------------------------------------
// QKV projection, 128x128 tile, BK=32, register-double-buffered.
// r17: LDS 73728 -> 40960 B (3 blocks/CU, was 2; 768-block grid = 3x256
// packs with ZERO tail). Both X and W staged as bf16 uint4 (no cvt).
// Row stride 40 u16 = 80 B keeps every uint4 LDS access 16B-aligned.
// Masked keys still ZEROED at projection time for K (mode 1) / V (mode 2).
// ---------------------------------------------------------------------------
__launch_bounds__(256, 3)
__global__ void proj_qkv(const u16* __restrict__ xbf,
                         const u16* __restrict__ wbf,
                         const float* __restrict__ bq, const float* __restrict__ bk,
                         const float* __restrict__ bv,
                         const int* __restrict__ mask,
                         u16* __restrict__ qo, u16* __restrict__ ko, u16* __restrict__ vo)
{
    const int mode = blockIdx.z;
    const u16* X      = xbf + (size_t)mode * ((size_t)NB * LSEQ * DM);
    const u16* Wb     = wbf + (size_t)mode * DM * DM;
    const float* bias = (mode == 0) ? bq : (mode == 1) ? bk : bv;
    u16* out          = (mode == 0) ? qo : (mode == 1) ? ko : vo;

    __shared__ __align__(16) u16 sbuf[2][2][128][40];
    u16 (*As)[128][40] = sbuf[0];
    u16 (*Bs)[128][40] = sbuf[1];

    const int tid  = threadIdx.x;
    const int wave = tid >> 6;
    const int lane = tid & 63;
    const int g    = lane >> 4;
    const int ln   = lane & 15;
    const int wr   = wave >> 1;
    const int wc   = wave & 1;

    const int m0 = blockIdx.x * 128;
    const int n0 = blockIdx.y * 128;

    uint4 xa[2], wa[2];
    #pragma unroll
    for (int i = 0; i < 2; ++i) {
        int idx = tid + 256 * i;
        int row = idx >> 2;
        int col = (idx & 3) * 8;
        xa[i] = *(const uint4*)(X  + (size_t)(m0 + row) * DM + col);
        wa[i] = *(const uint4*)(Wb + (size_t)(n0 + row) * DM + col);
    }
    #pragma unroll
    for (int i = 0; i < 2; ++i) {
        int idx = tid + 256 * i;
        int row = idx >> 2;
        int col = (idx & 3) * 8;
        *(uint4*)&As[0][row][col] = xa[i];
        *(uint4*)&Bs[0][row][col] = wa[i];
    }

    f32x4 acc[4][4] = {};

    for (int kt = 0; kt < 16; ++kt) {
        const int cur = kt & 1;
        __syncthreads();

        if (kt < 15) {
            int kb = (kt + 1) * 32;
            #pragma unroll
            for (int i = 0; i < 2; ++i) {
                int idx = tid + 256 * i;
                int row = idx >> 2;
                int col = (idx & 3) * 8;
                xa[i] = *(const uint4*)(X  + (size_t)(m0 + row) * DM + kb + col);
                wa[i] = *(const uint4*)(Wb + (size_t)(n0 + row) * DM + kb + col);
            }
        }

        bf16x8 af[4], bf[4];
        #pragma unroll
        for (int t = 0; t < 4; ++t) {
            af[t] = *(const bf16x8*)&As[cur][wr * 64 + t * 16 + ln][g * 8];
            bf[t] = *(const bf16x8*)&Bs[cur][wc * 64 + t * 16 + ln][g * 8];
        }
        #pragma unroll
        for (int mt = 0; mt < 4; ++mt)
            #pragma unroll
            for (int nt = 0; nt < 4; ++nt)
                acc[mt][nt] = mfma32(af[mt], bf[nt], acc[mt][nt]);

        if (kt < 15) {
            int nxt = 1 - cur;
            #pragma unroll
            for (int i = 0; i < 2; ++i) {
                int idx = tid + 256 * i;
                int row = idx >> 2;
                int col = (idx & 3) * 8;
                *(uint4*)&As[nxt][row][col] = xa[i];
                *(uint4*)&Bs[nxt][row][col] = wa[i];
            }
        }
    }

    if (mode != 2) {
        #pragma unroll
        for (int nt = 0; nt < 4; ++nt) {
            int n  = n0 + wc * 64 + nt * 16 + ln;
            float bias_n = bias[n];
            int hh = n >> 6;
            int d  = n & (DK - 1);
            #pragma unroll
            for (int mt = 0; mt < 4; ++mt)
                #pragma unroll
                for (int r = 0; r < 4; ++r) {
                    int m  = m0 + wr * 64 + mt * 16 + g * 4 + r;
                    int bb = m >> 12;
                    int s  = m & (LSEQ - 1);
                    float val = acc[mt][nt][r] + bias_n;
                    if (mode == 0) val *= QSCALE;
                    else           val = mask[bb * LSEQ + s] ? val : 0.0f;  // zero masked K rows
                    out[(size_t)((bb * H + hh) * LSEQ + s) * DK + d] = f2bf(val);
                }
        }
    } else {
        __syncthreads();   // all waves done reading sbuf before reuse as Ts
        u16* Ts = &sbuf[0][0][0][0];   // 40960 B total >= 128*136*2 = 34816 B
        const int bb = m0 >> 12;
        const int s0 = m0 & (LSEQ - 1);
        #pragma unroll
        for (int nt = 0; nt < 4; ++nt) {
            int dl = wc * 64 + nt * 16 + ln;
            float bias_n = bias[n0 + dl];
            #pragma unroll
            for (int mt = 0; mt < 4; ++mt)
                #pragma unroll
                for (int r = 0; r < 4; ++r) {
                    int sl = wr * 64 + mt * 16 + g * 4 + r;
                    float val = acc[mt][nt][r] + bias_n;
                    val = mask[bb * LSEQ + s0 + sl] ? val : 0.0f;           // zero masked V rows
                    Ts[dl * 136 + sl] = f2bf(val);
                }
        }
        __syncthreads();
        int dl   = tid >> 1;
        int half = tid & 1;
        int n  = n0 + dl;
        int hh = n >> 6;
        int d  = n & (DK - 1);
        int sb = s0 + half * 64;
        u16* dst = out + ((size_t)((bb * H + hh) * DK + d) * LSEQ + sb);
        const u16* srcp = Ts + dl * 136 + half * 64;
        #pragma unroll
        for (int i = 0; i < 8; ++i)
            *(uint4*)(dst + i * 8) = *(const uint4*)(srcp + i * 8);
    }
}

// ---------------------------------------------------------------------------
// Flash attention, transposed-S, q=32/wave, 4-way split-K.
// r17: EXACT r13 body (best measured: 81.7 us in r16, stable across 3 runs).
// LESSONS pinned: (r12) no source-level PV pipelining — spills; (r14) K and
// V must stay LDS-staged — L1-resident global reads expose latency before
// the dependent MFMAs (83 -> 148 us); (r15) fusing the split-combine into a
// consumer that re-reads each element 8x is an 8x work multiplier.
// RULES (r5/r7/r10): never force VGPR below natural 64; no control flow
// between the QK^T MFMAs and the P-pack; WRITE_SIZE ~34 MB good,
// 100s of MB = spill -> revert.
// ---------------------------------------------------------------------------
__launch_bounds__(256, 4)
__global__ void flash(const u16* __restrict__ qws, const u16* __restrict__ kws,
                      const u16* __restrict__ vws, const int* __restrict__ mask,
                      u16* __restrict__ Opart, float* __restrict__ lpart)
{
    __shared__ u16 Ks[2][64][64];
    __shared__ u16 Vs[2][64][64];   // [d][pi(key)], slot-swizzled

    const int tid   = threadIdx.x;
    const int wave  = tid >> 6;
    const int lane  = tid & 63;
    const int g     = lane >> 4;
    const int ln    = lane & 15;
    const int b     = blockIdx.z;
    const int h     = blockIdx.y;
    const int qblk  = blockIdx.x & 31;
    const int split = blockIdx.x >> 5;
    const int q0    = qblk * 128;
    const int kstart = split * KSPAN;

    const u16* qp = qws + ((size_t)((b * H + h) * LSEQ) + q0 + wave * 32 + ln) * DK;
    const u16* kp = kws + (size_t)(b * H + h) * LSEQ * DK;
    const u16* vp = vws + (size_t)(b * H + h) * DK * LSEQ;
    const int* mp = mask + b * LSEQ;

    // count masked keys in this split (wave-uniform; hot loop is mask-free)
    int nmask = 0;
    for (int t = 0; t < NIT; ++t) {
        int mval = mp[kstart + t * 64 + lane];
        unsigned long long bal = __ballot(mval == 0);
        nmask += (int)__popcll(bal);
    }
    const float fnmask = (float)nmask;

    bf16x8 qf[2][2];
    qf[0][0] = *(const bf16x8*)(qp + g * 8);
    qf[0][1] = *(const bf16x8*)(qp + 32 + g * 8);
    qf[1][0] = *(const bf16x8*)(qp + 16 * DK + g * 8);
    qf[1][1] = *(const bf16x8*)(qp + 16 * DK + 32 + g * 8);

    union OU { unsigned u[4]; bf16x8 v; } onesu;
    onesu.u[0] = onesu.u[1] = onesu.u[2] = onesu.u[3] = 0x3F803F80u;
    const bf16x8 vones = onesu.v;

    f32x4 accO[2][4] = {};
    f32x4 accL[2] = {};
    const f32x4 fzero = {};   // loop-invariant zero C-in for the QK chains

    // --- staging-side swizzle constants (loop-invariant per lane) ---
    const int row = tid >> 3;
    const int c   = tid & 7;
    const int swz = row & 7;                       // (row+32)&7 == row&7
    const int kcol = (c ^ swz) * 8;                // K write: 16B slot c
    const int vcol0 = ((2 * c) & 3) * 16 + (c >> 1) * 4;
    const int vs0 = vcol0 >> 3;                    // V write: first 8B piece's slot
    const int vof = vcol0 & 7;
    const int vw0 = ((vs0 ^ swz) * 8) + vof;
    const int vw1 = (((vs0 + 2) ^ swz) * 8) + vof; // +16 u16 == +2 slots
    // --- read-side swizzle constant ---
    const int rs = ln & 7;                         // row&7 for rows kb*16+ln

    uint4 kr0, kr1, vr0, vr1;
    kr0 = *(const uint4*)(kp + (size_t)(kstart + row) * DK + c * 8);
    kr1 = *(const uint4*)(kp + (size_t)(kstart + row + 32) * DK + c * 8);
    vr0 = *(const uint4*)(vp + (size_t)row * LSEQ + kstart + c * 8);
    vr1 = *(const uint4*)(vp + (size_t)(row + 32) * LSEQ + kstart + c * 8);
    *(uint4*)&Ks[0][row][kcol]      = kr0;
    *(uint4*)&Ks[0][row + 32][kcol] = kr1;
    *(uint2*)&Vs[0][row][vw0]       = make_uint2(vr0.x, vr0.y);
    *(uint2*)&Vs[0][row][vw1]       = make_uint2(vr0.z, vr0.w);
    *(uint2*)&Vs[0][row + 32][vw0]  = make_uint2(vr1.x, vr1.y);
    *(uint2*)&Vs[0][row + 32][vw1]  = make_uint2(vr1.z, vr1.w);

    for (int it = 0; it < NIT; ++it) {
        const int cur = it & 1;
        __syncthreads();

        if (it < NIT - 1) {
            int kn = kstart + it * 64 + 64;
            kr0 = *(const uint4*)(kp + (size_t)(kn + row) * DK + c * 8);
            kr1 = *(const uint4*)(kp + (size_t)(kn + row + 32) * DK + c * 8);
            vr0 = *(const uint4*)(vp + (size_t)row * LSEQ + kn + c * 8);
            vr1 = *(const uint4*)(vp + (size_t)(row + 32) * LSEQ + kn + c * 8);
        }

        // S^T = K . Q^T for both q-subtiles (K-frags read once)
        __builtin_amdgcn_s_setprio(1);
        f32x4 sc[2][4];
        #pragma unroll
        for (int kb = 0; kb < 4; ++kb) {
            bf16x8 kf0 = *(const bf16x8*)&Ks[cur][kb * 16 + ln][(g ^ rs) * 8];
            bf16x8 kf1 = *(const bf16x8*)&Ks[cur][kb * 16 + ln][((g + 4) ^ rs) * 8];
            #pragma unroll
            for (int j = 0; j < 2; ++j) {
                f32x4 z = mfma32(kf0, qf[j][0], fzero);
                z = mfma32(kf1, qf[j][1], z);
                sc[j][kb] = z;
            }
        }
        __builtin_amdgcn_s_setprio(0);

        // exp2 directly — mask already baked into K (s=0 -> p=1, V=0)
        #pragma unroll
        for (int kb = 0; kb < 4; ++kb)
            #pragma unroll
            for (int j = 0; j < 2; ++j) {
                sc[j][kb][0] = fexp2(sc[j][kb][0]);
                sc[j][kb][1] = fexp2(sc[j][kb][1]);
                sc[j][kb][2] = fexp2(sc[j][kb][2]);
                sc[j][kb][3] = fexp2(sc[j][kb][3]);
            }

        // pack P fragments (score regs are A-layout under formal-k remap)
        union PU { unsigned u[4]; bf16x8 v; } p01[2], p23[2];
        #pragma unroll
        for (int j = 0; j < 2; ++j) {
            p01[j].u[0] = pkbf(sc[j][0][0], sc[j][0][1]);
            p01[j].u[1] = pkbf(sc[j][0][2], sc[j][0][3]);
            p01[j].u[2] = pkbf(sc[j][1][0], sc[j][1][1]);
            p01[j].u[3] = pkbf(sc[j][1][2], sc[j][1][3]);
            p23[j].u[0] = pkbf(sc[j][2][0], sc[j][2][1]);
            p23[j].u[1] = pkbf(sc[j][2][2], sc[j][2][3]);
            p23[j].u[2] = pkbf(sc[j][3][0], sc[j][3][1]);
            p23[j].u[3] = pkbf(sc[j][3][2], sc[j][3][3]);
        }

        // l row-sums via ones-MFMA; O += P . V
        __builtin_amdgcn_s_setprio(1);
        #pragma unroll
        for (int j = 0; j < 2; ++j) {
            accL[j] = mfma32(p01[j].v, vones, accL[j]);
            accL[j] = mfma32(p23[j].v, vones, accL[j]);
        }
        #pragma unroll
        for (int t = 0; t < 4; ++t) {
            bf16x8 vb01 = *(const bf16x8*)&Vs[cur][t * 16 + ln][((2 * g) ^ rs) * 8];
            bf16x8 vb23 = *(const bf16x8*)&Vs[cur][t * 16 + ln][((2 * g + 1) ^ rs) * 8];
            #pragma unroll
            for (int j = 0; j < 2; ++j) {
                accO[j][t] = mfma32(p01[j].v, vb01, accO[j][t]);
                accO[j][t] = mfma32(p23[j].v, vb23, accO[j][t]);
            }
        }
        __builtin_amdgcn_s_setprio(0);

        if (it < NIT - 1) {
            int nxt = 1 - cur;
            *(uint4*)&Ks[nxt][row][kcol]      = kr0;
            *(uint4*)&Ks[nxt][row + 32][kcol] = kr1;
            *(uint2*)&Vs[nxt][row][vw0]       = make_uint2(vr0.x, vr0.y);
            *(uint2*)&Vs[nxt][row][vw1]       = make_uint2(vr0.z, vr0.w);
            *(uint2*)&Vs[nxt][row + 32][vw0]  = make_uint2(vr1.x, vr1.y);
            *(uint2*)&Vs[nxt][row + 32][vw1]  = make_uint2(vr1.z, vr1.w);
        }
    }

    // accL[j][r] = l + n_masked for q-row (g*4+r); subtract the exact overcount.
    const size_t PLANE = (size_t)NB * LSEQ * DM;
    u16* opp = Opart + (size_t)split * PLANE;

    #pragma unroll
    for (int j = 0; j < 2; ++j) {
        if (ln == 0) {
            #pragma unroll
            for (int r = 0; r < 4; ++r)
                lpart[(size_t)split * (NB * H * LSEQ) + ((size_t)(b * H + h) * LSEQ)
                      + q0 + wave * 32 + j * 16 + g * 4 + r] = accL[j][r] - fnmask;
        }
        #pragma unroll
        for (int r = 0; r < 4; ++r) {
            float linv = 1.0f / (accL[j][r] - fnmask);
            size_t base = ((size_t)(b * LSEQ) + q0 + wave * 32 + j * 16 + g * 4 + r) * DM + h * DK;
            #pragma unroll
            for (int t = 0; t < 4; ++t)
                opp[base + t * 16 + ln] = f2bf(accO[j][t][r] * linv);
        }
    }
}

// ---------------------------------------------------------------------------
// Split-K combine over NSPLIT partials: ows = sum_s (l_s * Ohat_s) / sum_s l_s.
// (r15 lesson: keep this standalone — each element combined exactly once at
// full occupancy; fusing into proj_out multiplied the work 8x.)
// ---------------------------------------------------------------------------
__launch_bounds__(256, 4)
__global__ void reduce_split(const u16* __restrict__ Opart, const float* __restrict__ lpart,
                             u16* __restrict__ ows)
{
    const size_t PLANE = (size_t)NB * LSEQ * DM;
    const size_t LP    = (size_t)NB * H * LSEQ;
    size_t gid  = (size_t)blockIdx.x * 256 + threadIdx.x;
    size_t flat = gid * 8;

    int b   = (int)(flat >> 21);            // LSEQ*DM = 2^21
    int rem = (int)(flat & ((1 << 21) - 1));
    int q   = rem >> 9;                      // DM = 512
    int hh  = (rem & 511) >> 6;
    size_t lidx = ((size_t)(b * H + hh) * LSEQ) + q;

    float ls[NSPLIT];
    float lsum = 0.0f;
    #pragma unroll
    for (int s = 0; s < NSPLIT; ++s) {
        ls[s] = lpart[(size_t)s * LP + lidx];
        lsum += ls[s];
    }
    float inv = 1.0f / lsum;

    float o[8] = {};
    #pragma unroll
    for (int s = 0; s < NSPLIT; ++s) {
        float w = ls[s] * inv;
        uint4 cc = *(const uint4*)(Opart + (size_t)s * PLANE + flat);
        float2 a;
        a = ubf2(cc.x); o[0] += w * a.x; o[1] += w * a.y;
        a = ubf2(cc.y); o[2] += w * a.x; o[3] += w * a.y;
        a = ubf2(cc.z); o[4] += w * a.x; o[5] += w * a.y;
        a = ubf2(cc.w); o[6] += w * a.x; o[7] += w * a.y;
    }
    uint4 r;
    r.x = pkbf(o[0], o[1]);
    r.y = pkbf(o[2], o[3]);
    r.z = pkbf(o[4], o[5]);
    r.w = pkbf(o[6], o[7]);
    *(uint4*)(ows + flat) = r;
}

// ---------------------------------------------------------------------------
// Output projection, 128x64 tile, BK=32, register-double-buffered.
// r17: LDS 52224 -> 30720 B => 5 blocks/CU (was 3). A and Wo staged as
// bf16 uint4; row stride 40 u16 keeps LDS uint4 accesses 16B-aligned.
// ---------------------------------------------------------------------------
__launch_bounds__(256, 4)
__global__ void proj_out(const u16* __restrict__ A, const u16* __restrict__ Wob,
                         const float* __restrict__ bo, float* __restrict__ out)
{
    __shared__ __align__(16) u16 As2[2][128][40];
    __shared__ __align__(16) u16 Bs2[2][64][40];

    const int tid  = threadIdx.x;
    const int wave = tid >> 6;
    const int lane = tid & 63;
    const int g    = lane >> 4;
    const int ln   = lane & 15;

    const int m0 = blockIdx.x * 128;
    const int n0 = blockIdx.y * 64;

    uint4 aa[2], wa;
    #pragma unroll
    for (int i = 0; i < 2; ++i) {
        int idx = tid + 256 * i;
        int row = idx >> 2;
        int col = (idx & 3) * 8;
        aa[i] = *(const uint4*)(A + (size_t)(m0 + row) * DM + col);
    }
    {
        int row = tid >> 2;
        int col = (tid & 3) * 8;
        wa = *(const uint4*)(Wob + (size_t)(n0 + row) * DM + col);
    }
    #pragma unroll
    for (int i = 0; i < 2; ++i) {
        int idx = tid + 256 * i;
        int row = idx >> 2;
        int col = (idx & 3) * 8;
        *(uint4*)&As2[0][row][col] = aa[i];
    }
    {
        int row = tid >> 2;
        int col = (tid & 3) * 8;
        *(uint4*)&Bs2[0][row][col] = wa;
    }

    f32x4 acc[2][4] = {};

    for (int kt = 0; kt < 16; ++kt) {
        const int cur = kt & 1;
        __syncthreads();

        if (kt < 15) {
            int kb = (kt + 1) * 32;
            #pragma unroll
            for (int i = 0; i < 2; ++i) {
                int idx = tid + 256 * i;
                int row = idx >> 2;
                int col = (idx & 3) * 8;
                aa[i] = *(const uint4*)(A + (size_t)(m0 + row) * DM + kb + col);
            }
            int row = tid >> 2;
            int col = (tid & 3) * 8;
            wa = *(const uint4*)(Wob + (size_t)(n0 + row) * DM + kb + col);
        }

        bf16x8 af[2], bf[4];
        #pragma unroll
        for (int mt = 0; mt < 2; ++mt)
            af[mt] = *(const bf16x8*)&As2[cur][wave * 32 + mt * 16 + ln][g * 8];
        #pragma unroll
        for (int nt = 0; nt < 4; ++nt)
            bf[nt] = *(const bf16x8*)&Bs2[cur][nt * 16 + ln][g * 8];
        #pragma unroll
        for (int mt = 0; mt < 2; ++mt)
            #pragma unroll
            for (int nt = 0; nt < 4; ++nt)
                acc[mt][nt] = mfma32(af[mt], bf[nt], acc[mt][nt]);

        if (kt < 15) {
            int nxt = 1 - cur;
            #pragma unroll
            for (int i = 0; i < 2; ++i) {
                int idx = tid + 256 * i;
                int row = idx >> 2;
                int col = (idx & 3) * 8;
                *(uint4*)&As2[nxt][row][col] = aa[i];
            }
            int row = tid >> 2;
            int col = (tid & 3) * 8;
            *(uint4*)&Bs2[nxt][row][col] = wa;
        }
    }

    #pragma unroll
    for (int nt = 0; nt < 4; ++nt) {
        int n = n0 + nt * 16 + ln;
        float bias_n = bo[n];
        #pragma unroll
        for (int mt = 0; mt < 2; ++mt)
            #pragma unroll
            for (int r = 0; r < 4; ++r) {
                int m = m0 + wave * 32 + mt * 16 + g * 4 + r;
                out[(size_t)m * DM + n] = acc[mt][nt][r] + bias_n;
            }
    }
}

// ---------------------------------------------------------------------------
extern "C" void kernel_launch(void* const* d_in, const int* in_sizes, int n_in,
                              void* d_out, int out_size, void* d_ws, size_t ws_size,
                              hipStream_t stream) {
    (void)in_sizes; (void)n_in; (void)out_size; (void)ws_size;

    const float* query = (const float*)d_in[0];
    const float* key   = (const float*)d_in[1];
    const float* value = (const float*)d_in[2];
    const int*   mask  = (const int*)d_in[3];
    const float* Wq = (const float*)d_in[4];
    const float* bq = (const float*)d_in[5];
    const float* Wk = (const float*)d_in[6];
    const float* bk = (const float*)d_in[7];
    const float* Wv = (const float*)d_in[8];
    const float* bv = (const float*)d_in[9];
    const float* Wo = (const float*)d_in[10];
    const float* bo = (const float*)d_in[11];
    float* out = (float*)d_out;

    // ws layout (u16 elems): qws | kws | vws | ows | Opart(NSPLIT planes) |
    //                        lpart(f32) | wbf (4x 512x512 bf16)
    // xbf ALIASES Opart's first 3 planes: cvt_all writes it, proj_qkv reads
    // it, and only afterwards does flash overwrite Opart (stream-serial).
    const size_t PLANE = (size_t)NB * H * LSEQ * DK;   // 4,194,304
    u16* qws   = (u16*)d_ws;
    u16* kws   = qws + PLANE;
    u16* vws   = kws + PLANE;
    u16* ows   = vws + PLANE;
    u16* Opart = ows + PLANE;
    float* lpart = (float*)(Opart + (size_t)NSPLIT * PLANE);
    u16* wbf   = (u16*)(lpart + (size_t)NSPLIT * NB * H * LSEQ);
    u16* xbf   = Opart;   // 3 planes, dead until flash runs

    dim3 blk(256);
    cvt_all<<<dim3(2048, 7), blk, 0, stream>>>(Wq, Wk, Wv, Wo, query, key, value,
                                               wbf, xbf);
    proj_qkv<<<dim3(64, 4, 3), blk, 0, stream>>>(xbf, wbf, bq, bk, bv, mask,
                                                 qws, kws, vws);
    flash<<<dim3(32 * NSPLIT, H, NB), blk, 0, stream>>>(qws, kws, vws, mask, Opart, lpart);
    reduce_split<<<dim3(2048), blk, 0, stream>>>(Opart, lpart, ows);
    proj_out<<<dim3(64, 8, 1), blk, 0, stream>>>(ows, wbf + 3 * (size_t)DM * DM, bo, out);
}

// Round 10
// 230.158 us; speedup vs baseline: 1.0339x; 1.0339x over previous
//
#include <hip/hip_runtime.h>
#include <hip/hip_bf16.h>

#define H 8
#define DM 512
#define DK 64
#define LSEQ 4096
#define NB 2
#define NSPLIT 4
#define KSPAN (LSEQ / NSPLIT)   // keys per split = 1024
#define NIT (KSPAN / 64)        // 16 k-tiles per block

// 0.125 (1/sqrt(DK)) * log2(e): folded into Q so softmax uses exp2 directly
#define QSCALE 0.18033688011112042f

typedef float f32x4 __attribute__((ext_vector_type(4)));
typedef __bf16 bf16x8 __attribute__((ext_vector_type(8)));
typedef __bf16 bf16x2 __attribute__((ext_vector_type(2)));
typedef unsigned short u16;

__device__ __forceinline__ u16 f2bf(float f) {
    union { float f; unsigned u; } v{f};
    return (u16)((v.u + 0x8000u) >> 16);
}

__device__ __forceinline__ unsigned pkbf(float a, float b) {
#if __has_builtin(__builtin_amdgcn_cvt_pk_bf16_f32)
    union { bf16x2 v; unsigned u; } x;
    x.v = __builtin_amdgcn_cvt_pk_bf16_f32(a, b);
    return x.u;
#else
    union { float f; unsigned u; } x{a}, y{b};
    return ((x.u + 0x8000u) >> 16) | ((y.u + 0x8000u) & 0xffff0000u);
#endif
}

__device__ __forceinline__ ushort4 cvt4(float4 a) {
    union { ushort4 s; uint2 u; } o;
    o.u.x = pkbf(a.x, a.y);
    o.u.y = pkbf(a.z, a.w);
    return o.s;
}

__device__ __forceinline__ float2 ubf2(unsigned u) {
    union { float f; unsigned v; } a, b;
    a.v = u << 16;
    b.v = u & 0xffff0000u;
    return make_float2(a.f, b.f);
}

__device__ __forceinline__ float fexp2(float x) {
#if __has_builtin(__builtin_amdgcn_exp2f)
    return __builtin_amdgcn_exp2f(x);
#else
    return exp2f(x);
#endif
}

__device__ __forceinline__ f32x4 mfma32(bf16x8 a, bf16x8 b, f32x4 c) {
    return __builtin_amdgcn_mfma_f32_16x16x32_bf16(a, b, c, 0, 0, 0);
}

// ---------------------------------------------------------------------------
// r18 (= r17's cvt_all, verified passing): one-shot fp32 -> bf16 conversion
// of the 4 weight matrices AND the 3 activation tensors. X is re-read 4x by
// proj_qkv's n-blocks — bf16 halves that traffic and deletes staging cvt
// VALU. Same pkbf RNE conversion -> bit-identical numerics.
// ---------------------------------------------------------------------------
__launch_bounds__(256, 8)
__global__ void cvt_all(const float* __restrict__ W0, const float* __restrict__ W1,
                        const float* __restrict__ W2, const float* __restrict__ W3,
                        const float* __restrict__ X0, const float* __restrict__ X1,
                        const float* __restrict__ X2,
                        u16* __restrict__ wout, u16* __restrict__ xout)
{
    const int y = blockIdx.y;
    const float* src;
    u16* dst;
    int nblk;
    if (y < 4) {
        src = (y == 0) ? W0 : (y == 1) ? W1 : (y == 2) ? W2 : W3;
        dst = wout + (size_t)y * DM * DM;
        nblk = (DM * DM) / (256 * 8);              // 128
    } else {
        src = (y == 4) ? X0 : (y == 5) ? X1 : X2;
        dst = xout + (size_t)(y - 4) * ((size_t)NB * LSEQ * DM);
        nblk = ((size_t)NB * LSEQ * DM) / (256 * 8); // 2048
    }
    if ((int)blockIdx.x >= nblk) return;
    size_t base = ((size_t)blockIdx.x * 256 + threadIdx.x) * 8;
    float4 a = *(const float4*)(src + base);
    float4 b = *(const float4*)(src + base + 4);
    *(ushort4*)(dst + base)     = cvt4(a);
    *(ushort4*)(dst + base + 4) = cvt4(b);
}

// ---------------------------------------------------------------------------
// QKV projection, 128x128 tile, BK=64, register-double-buffered — the r16
// structure (best measured) with BOTH X and W staged as bf16 uint4 copies.
// r17 LESSON: BK=32 doubled barriers and cost ~20 us — these GEMMs are
// barrier-bound; keep 8 k-steps. Masked keys ZEROED at projection time for
// K (mode 1) / V (mode 2) — keeps the mask out of flash's hot loop.
// ---------------------------------------------------------------------------
__launch_bounds__(256, 2)
__global__ void proj_qkv(const u16* __restrict__ xbf,
                         const u16* __restrict__ wbf,
                         const float* __restrict__ bq, const float* __restrict__ bk,
                         const float* __restrict__ bv,
                         const int* __restrict__ mask,
                         u16* __restrict__ qo, u16* __restrict__ ko, u16* __restrict__ vo)
{
    const int mode = blockIdx.z;
    const u16* X      = xbf + (size_t)mode * ((size_t)NB * LSEQ * DM);
    const u16* Wb     = wbf + (size_t)mode * DM * DM;
    const float* bias = (mode == 0) ? bq : (mode == 1) ? bk : bv;
    u16* out          = (mode == 0) ? qo : (mode == 1) ? ko : vo;

    __shared__ __align__(16) u16 As[2][128][72];
    __shared__ __align__(16) u16 Bs[2][128][72];

    const int tid  = threadIdx.x;
    const int wave = tid >> 6;
    const int lane = tid & 63;
    const int g    = lane >> 4;
    const int ln   = lane & 15;
    const int wr   = wave >> 1;
    const int wc   = wave & 1;

    const int m0 = blockIdx.x * 128;
    const int n0 = blockIdx.y * 128;

    uint4 xa[4], wa[4];
    #pragma unroll
    for (int i = 0; i < 4; ++i) {
        int idx = tid + 256 * i;
        int row = idx >> 3;
        int col = (idx & 7) * 8;
        xa[i] = *(const uint4*)(X  + (size_t)(m0 + row) * DM + col);
        wa[i] = *(const uint4*)(Wb + (size_t)(n0 + row) * DM + col);
    }
    #pragma unroll
    for (int i = 0; i < 4; ++i) {
        int idx = tid + 256 * i;
        int row = idx >> 3;
        int col = (idx & 7) * 8;
        *(uint4*)&As[0][row][col] = xa[i];
        *(uint4*)&Bs[0][row][col] = wa[i];
    }

    f32x4 acc[4][4] = {};

    for (int kt = 0; kt < 8; ++kt) {
        const int cur = kt & 1;
        __syncthreads();

        if (kt < 7) {
            int kb = (kt + 1) * 64;
            #pragma unroll
            for (int i = 0; i < 4; ++i) {
                int idx = tid + 256 * i;
                int row = idx >> 3;
                int col = (idx & 7) * 8;
                xa[i] = *(const uint4*)(X  + (size_t)(m0 + row) * DM + kb + col);
                wa[i] = *(const uint4*)(Wb + (size_t)(n0 + row) * DM + kb + col);
            }
        }

        bf16x8 af[4][2], bf[4][2];
        #pragma unroll
        for (int t = 0; t < 4; ++t) {
            af[t][0] = *(const bf16x8*)&As[cur][wr * 64 + t * 16 + ln][g * 8];
            af[t][1] = *(const bf16x8*)&As[cur][wr * 64 + t * 16 + ln][32 + g * 8];
            bf[t][0] = *(const bf16x8*)&Bs[cur][wc * 64 + t * 16 + ln][g * 8];
            bf[t][1] = *(const bf16x8*)&Bs[cur][wc * 64 + t * 16 + ln][32 + g * 8];
        }
        #pragma unroll
        for (int mt = 0; mt < 4; ++mt)
            #pragma unroll
            for (int nt = 0; nt < 4; ++nt) {
                acc[mt][nt] = mfma32(af[mt][0], bf[nt][0], acc[mt][nt]);
                acc[mt][nt] = mfma32(af[mt][1], bf[nt][1], acc[mt][nt]);
            }

        if (kt < 7) {
            int nxt = 1 - cur;
            #pragma unroll
            for (int i = 0; i < 4; ++i) {
                int idx = tid + 256 * i;
                int row = idx >> 3;
                int col = (idx & 7) * 8;
                *(uint4*)&As[nxt][row][col] = xa[i];
                *(uint4*)&Bs[nxt][row][col] = wa[i];
            }
        }
    }

    if (mode != 2) {
        #pragma unroll
        for (int nt = 0; nt < 4; ++nt) {
            int n  = n0 + wc * 64 + nt * 16 + ln;
            float bias_n = bias[n];
            int hh = n >> 6;
            int d  = n & (DK - 1);
            #pragma unroll
            for (int mt = 0; mt < 4; ++mt)
                #pragma unroll
                for (int r = 0; r < 4; ++r) {
                    int m  = m0 + wr * 64 + mt * 16 + g * 4 + r;
                    int bb = m >> 12;
                    int s  = m & (LSEQ - 1);
                    float val = acc[mt][nt][r] + bias_n;
                    if (mode == 0) val *= QSCALE;
                    else           val = mask[bb * LSEQ + s] ? val : 0.0f;  // zero masked K rows
                    out[(size_t)((bb * H + hh) * LSEQ + s) * DK + d] = f2bf(val);
                }
        }
    } else {
        __syncthreads();   // all waves done reading As before reuse as Ts
        u16* Ts = &As[0][0][0];
        const int bb = m0 >> 12;
        const int s0 = m0 & (LSEQ - 1);
        #pragma unroll
        for (int nt = 0; nt < 4; ++nt) {
            int dl = wc * 64 + nt * 16 + ln;
            float bias_n = bias[n0 + dl];
            #pragma unroll
            for (int mt = 0; mt < 4; ++mt)
                #pragma unroll
                for (int r = 0; r < 4; ++r) {
                    int sl = wr * 64 + mt * 16 + g * 4 + r;
                    float val = acc[mt][nt][r] + bias_n;
                    val = mask[bb * LSEQ + s0 + sl] ? val : 0.0f;           // zero masked V rows
                    Ts[dl * 136 + sl] = f2bf(val);
                }
        }
        __syncthreads();
        int dl   = tid >> 1;
        int half = tid & 1;
        int n  = n0 + dl;
        int hh = n >> 6;
        int d  = n & (DK - 1);
        int sb = s0 + half * 64;
        u16* dst = out + ((size_t)((bb * H + hh) * DK + d) * LSEQ + sb);
        const u16* srcp = Ts + dl * 136 + half * 64;
        #pragma unroll
        for (int i = 0; i < 8; ++i)
            *(uint4*)(dst + i * 8) = *(const uint4*)(srcp + i * 8);
    }
}

// ---------------------------------------------------------------------------
// Flash attention, transposed-S, q=32/wave, 4-way split-K.
// r18: EXACT r13 body (stable 81.7-83.5 us across 4 rounds).
// LESSONS pinned: (r12) no source-level PV pipelining — spills; (r14) K and
// V must stay LDS-staged — L1-resident global reads expose latency before
// the dependent MFMAs (83 -> 148 us); (r15) fusing the split-combine into a
// consumer that re-reads each element 8x is an 8x work multiplier; (r17)
// never trade barrier count for occupancy in the GEMMs.
// RULES (r5/r7/r10): never force VGPR below natural 64; no control flow
// between the QK^T MFMAs and the P-pack; WRITE_SIZE ~34 MB good,
// 100s of MB = spill -> revert.
// ---------------------------------------------------------------------------
__launch_bounds__(256, 4)
__global__ void flash(const u16* __restrict__ qws, const u16* __restrict__ kws,
                      const u16* __restrict__ vws, const int* __restrict__ mask,
                      u16* __restrict__ Opart, float* __restrict__ lpart)
{
    __shared__ u16 Ks[2][64][64];
    __shared__ u16 Vs[2][64][64];   // [d][pi(key)], slot-swizzled

    const int tid   = threadIdx.x;
    const int wave  = tid >> 6;
    const int lane  = tid & 63;
    const int g     = lane >> 4;
    const int ln    = lane & 15;
    const int b     = blockIdx.z;
    const int h     = blockIdx.y;
    const int qblk  = blockIdx.x & 31;
    const int split = blockIdx.x >> 5;
    const int q0    = qblk * 128;
    const int kstart = split * KSPAN;

    const u16* qp = qws + ((size_t)((b * H + h) * LSEQ) + q0 + wave * 32 + ln) * DK;
    const u16* kp = kws + (size_t)(b * H + h) * LSEQ * DK;
    const u16* vp = vws + (size_t)(b * H + h) * DK * LSEQ;
    const int* mp = mask + b * LSEQ;

    // count masked keys in this split (wave-uniform; hot loop is mask-free)
    int nmask = 0;
    for (int t = 0; t < NIT; ++t) {
        int mval = mp[kstart + t * 64 + lane];
        unsigned long long bal = __ballot(mval == 0);
        nmask += (int)__popcll(bal);
    }
    const float fnmask = (float)nmask;

    bf16x8 qf[2][2];
    qf[0][0] = *(const bf16x8*)(qp + g * 8);
    qf[0][1] = *(const bf16x8*)(qp + 32 + g * 8);
    qf[1][0] = *(const bf16x8*)(qp + 16 * DK + g * 8);
    qf[1][1] = *(const bf16x8*)(qp + 16 * DK + 32 + g * 8);

    union OU { unsigned u[4]; bf16x8 v; } onesu;
    onesu.u[0] = onesu.u[1] = onesu.u[2] = onesu.u[3] = 0x3F803F80u;
    const bf16x8 vones = onesu.v;

    f32x4 accO[2][4] = {};
    f32x4 accL[2] = {};
    const f32x4 fzero = {};   // loop-invariant zero C-in for the QK chains

    // --- staging-side swizzle constants (loop-invariant per lane) ---
    const int row = tid >> 3;
    const int c   = tid & 7;
    const int swz = row & 7;                       // (row+32)&7 == row&7
    const int kcol = (c ^ swz) * 8;                // K write: 16B slot c
    const int vcol0 = ((2 * c) & 3) * 16 + (c >> 1) * 4;
    const int vs0 = vcol0 >> 3;                    // V write: first 8B piece's slot
    const int vof = vcol0 & 7;
    const int vw0 = ((vs0 ^ swz) * 8) + vof;
    const int vw1 = (((vs0 + 2) ^ swz) * 8) + vof; // +16 u16 == +2 slots
    // --- read-side swizzle constant ---
    const int rs = ln & 7;                         // row&7 for rows kb*16+ln

    uint4 kr0, kr1, vr0, vr1;
    kr0 = *(const uint4*)(kp + (size_t)(kstart + row) * DK + c * 8);
    kr1 = *(const uint4*)(kp + (size_t)(kstart + row + 32) * DK + c * 8);
    vr0 = *(const uint4*)(vp + (size_t)row * LSEQ + kstart + c * 8);
    vr1 = *(const uint4*)(vp + (size_t)(row + 32) * LSEQ + kstart + c * 8);
    *(uint4*)&Ks[0][row][kcol]      = kr0;
    *(uint4*)&Ks[0][row + 32][kcol] = kr1;
    *(uint2*)&Vs[0][row][vw0]       = make_uint2(vr0.x, vr0.y);
    *(uint2*)&Vs[0][row][vw1]       = make_uint2(vr0.z, vr0.w);
    *(uint2*)&Vs[0][row + 32][vw0]  = make_uint2(vr1.x, vr1.y);
    *(uint2*)&Vs[0][row + 32][vw1]  = make_uint2(vr1.z, vr1.w);

    for (int it = 0; it < NIT; ++it) {
        const int cur = it & 1;
        __syncthreads();

        if (it < NIT - 1) {
            int kn = kstart + it * 64 + 64;
            kr0 = *(const uint4*)(kp + (size_t)(kn + row) * DK + c * 8);
            kr1 = *(const uint4*)(kp + (size_t)(kn + row + 32) * DK + c * 8);
            vr0 = *(const uint4*)(vp + (size_t)row * LSEQ + kn + c * 8);
            vr1 = *(const uint4*)(vp + (size_t)(row + 32) * LSEQ + kn + c * 8);
        }

        // S^T = K . Q^T for both q-subtiles (K-frags read once)
        __builtin_amdgcn_s_setprio(1);
        f32x4 sc[2][4];
        #pragma unroll
        for (int kb = 0; kb < 4; ++kb) {
            bf16x8 kf0 = *(const bf16x8*)&Ks[cur][kb * 16 + ln][(g ^ rs) * 8];
            bf16x8 kf1 = *(const bf16x8*)&Ks[cur][kb * 16 + ln][((g + 4) ^ rs) * 8];
            #pragma unroll
            for (int j = 0; j < 2; ++j) {
                f32x4 z = mfma32(kf0, qf[j][0], fzero);
                z = mfma32(kf1, qf[j][1], z);
                sc[j][kb] = z;
            }
        }
        __builtin_amdgcn_s_setprio(0);

        // exp2 directly — mask already baked into K (s=0 -> p=1, V=0)
        #pragma unroll
        for (int kb = 0; kb < 4; ++kb)
            #pragma unroll
            for (int j = 0; j < 2; ++j) {
                sc[j][kb][0] = fexp2(sc[j][kb][0]);
                sc[j][kb][1] = fexp2(sc[j][kb][1]);
                sc[j][kb][2] = fexp2(sc[j][kb][2]);
                sc[j][kb][3] = fexp2(sc[j][kb][3]);
            }

        // pack P fragments (score regs are A-layout under formal-k remap)
        union PU { unsigned u[4]; bf16x8 v; } p01[2], p23[2];
        #pragma unroll
        for (int j = 0; j < 2; ++j) {
            p01[j].u[0] = pkbf(sc[j][0][0], sc[j][0][1]);
            p01[j].u[1] = pkbf(sc[j][0][2], sc[j][0][3]);
            p01[j].u[2] = pkbf(sc[j][1][0], sc[j][1][1]);
            p01[j].u[3] = pkbf(sc[j][1][2], sc[j][1][3]);
            p23[j].u[0] = pkbf(sc[j][2][0], sc[j][2][1]);
            p23[j].u[1] = pkbf(sc[j][2][2], sc[j][2][3]);
            p23[j].u[2] = pkbf(sc[j][3][0], sc[j][3][1]);
            p23[j].u[3] = pkbf(sc[j][3][2], sc[j][3][3]);
        }

        // l row-sums via ones-MFMA; O += P . V
        __builtin_amdgcn_s_setprio(1);
        #pragma unroll
        for (int j = 0; j < 2; ++j) {
            accL[j] = mfma32(p01[j].v, vones, accL[j]);
            accL[j] = mfma32(p23[j].v, vones, accL[j]);
        }
        #pragma unroll
        for (int t = 0; t < 4; ++t) {
            bf16x8 vb01 = *(const bf16x8*)&Vs[cur][t * 16 + ln][((2 * g) ^ rs) * 8];
            bf16x8 vb23 = *(const bf16x8*)&Vs[cur][t * 16 + ln][((2 * g + 1) ^ rs) * 8];
            #pragma unroll
            for (int j = 0; j < 2; ++j) {
                accO[j][t] = mfma32(p01[j].v, vb01, accO[j][t]);
                accO[j][t] = mfma32(p23[j].v, vb23, accO[j][t]);
            }
        }
        __builtin_amdgcn_s_setprio(0);

        if (it < NIT - 1) {
            int nxt = 1 - cur;
            *(uint4*)&Ks[nxt][row][kcol]      = kr0;
            *(uint4*)&Ks[nxt][row + 32][kcol] = kr1;
            *(uint2*)&Vs[nxt][row][vw0]       = make_uint2(vr0.x, vr0.y);
            *(uint2*)&Vs[nxt][row][vw1]       = make_uint2(vr0.z, vr0.w);
            *(uint2*)&Vs[nxt][row + 32][vw0]  = make_uint2(vr1.x, vr1.y);
            *(uint2*)&Vs[nxt][row + 32][vw1]  = make_uint2(vr1.z, vr1.w);
        }
    }

    // accL[j][r] = l + n_masked for q-row (g*4+r); subtract the exact overcount.
    const size_t PLANE = (size_t)NB * LSEQ * DM;
    u16* opp = Opart + (size_t)split * PLANE;

    #pragma unroll
    for (int j = 0; j < 2; ++j) {
        if (ln == 0) {
            #pragma unroll
            for (int r = 0; r < 4; ++r)
                lpart[(size_t)split * (NB * H * LSEQ) + ((size_t)(b * H + h) * LSEQ)
                      + q0 + wave * 32 + j * 16 + g * 4 + r] = accL[j][r] - fnmask;
        }
        #pragma unroll
        for (int r = 0; r < 4; ++r) {
            float linv = 1.0f / (accL[j][r] - fnmask);
            size_t base = ((size_t)(b * LSEQ) + q0 + wave * 32 + j * 16 + g * 4 + r) * DM + h * DK;
            #pragma unroll
            for (int t = 0; t < 4; ++t)
                opp[base + t * 16 + ln] = f2bf(accO[j][t][r] * linv);
        }
    }
}

// ---------------------------------------------------------------------------
// Split-K combine over NSPLIT partials: ows = sum_s (l_s * Ohat_s) / sum_s l_s.
// (r15 lesson: keep standalone — each element combined exactly once.)
// ---------------------------------------------------------------------------
__launch_bounds__(256, 4)
__global__ void reduce_split(const u16* __restrict__ Opart, const float* __restrict__ lpart,
                             u16* __restrict__ ows)
{
    const size_t PLANE = (size_t)NB * LSEQ * DM;
    const size_t LP    = (size_t)NB * H * LSEQ;
    size_t gid  = (size_t)blockIdx.x * 256 + threadIdx.x;
    size_t flat = gid * 8;

    int b   = (int)(flat >> 21);            // LSEQ*DM = 2^21
    int rem = (int)(flat & ((1 << 21) - 1));
    int q   = rem >> 9;                      // DM = 512
    int hh  = (rem & 511) >> 6;
    size_t lidx = ((size_t)(b * H + hh) * LSEQ) + q;

    float ls[NSPLIT];
    float lsum = 0.0f;
    #pragma unroll
    for (int s = 0; s < NSPLIT; ++s) {
        ls[s] = lpart[(size_t)s * LP + lidx];
        lsum += ls[s];
    }
    float inv = 1.0f / lsum;

    float o[8] = {};
    #pragma unroll
    for (int s = 0; s < NSPLIT; ++s) {
        float w = ls[s] * inv;
        uint4 cc = *(const uint4*)(Opart + (size_t)s * PLANE + flat);
        float2 a;
        a = ubf2(cc.x); o[0] += w * a.x; o[1] += w * a.y;
        a = ubf2(cc.y); o[2] += w * a.x; o[3] += w * a.y;
        a = ubf2(cc.z); o[4] += w * a.x; o[5] += w * a.y;
        a = ubf2(cc.w); o[6] += w * a.x; o[7] += w * a.y;
    }
    uint4 r;
    r.x = pkbf(o[0], o[1]);
    r.y = pkbf(o[2], o[3]);
    r.z = pkbf(o[4], o[5]);
    r.w = pkbf(o[6], o[7]);
    *(uint4*)(ows + flat) = r;
}

// ---------------------------------------------------------------------------
// Output projection, 128x64 tile, BK=64, register-double-buffered (r16
// verbatim: pad-68 => 52224 B, 3 blocks/CU; A and Wo staged as bf16 uint4).
// ---------------------------------------------------------------------------
__launch_bounds__(256, 3)
__global__ void proj_out(const u16* __restrict__ A, const u16* __restrict__ Wob,
                         const float* __restrict__ bo, float* __restrict__ out)
{
    __shared__ __align__(16) u16 As[2][128][68];
    __shared__ __align__(16) u16 Bs[2][64][68];

    const int tid  = threadIdx.x;
    const int wave = tid >> 6;
    const int lane = tid & 63;
    const int g    = lane >> 4;
    const int ln   = lane & 15;

    const int m0 = blockIdx.x * 128;
    const int n0 = blockIdx.y * 64;

    uint4 aa[4];
    uint4 wbb[2];
    #pragma unroll
    for (int i = 0; i < 4; ++i) {
        int idx = tid + 256 * i;
        int row = idx >> 3;
        int col = (idx & 7) * 8;
        aa[i] = *(const uint4*)(A + (size_t)(m0 + row) * DM + col);
    }
    #pragma unroll
    for (int i = 0; i < 2; ++i) {
        int idx = tid + 256 * i;
        int rwb = idx >> 3;
        int cwb = (idx & 7) * 8;
        wbb[i] = *(const uint4*)(Wob + (size_t)(n0 + rwb) * DM + cwb);
    }
    #pragma unroll
    for (int i = 0; i < 4; ++i) {
        int idx = tid + 256 * i;
        int row = idx >> 3;
        int col = (idx & 7) * 8;
        *(uint4*)&As[0][row][col] = aa[i];
    }
    #pragma unroll
    for (int i = 0; i < 2; ++i) {
        int idx = tid + 256 * i;
        int rwb = idx >> 3;
        int cwb = (idx & 7) * 8;
        *(uint4*)&Bs[0][rwb][cwb] = wbb[i];
    }

    f32x4 acc[2][4] = {};

    for (int kt = 0; kt < 8; ++kt) {
        const int cur = kt & 1;
        __syncthreads();

        if (kt < 7) {
            int kb = (kt + 1) * 64;
            #pragma unroll
            for (int i = 0; i < 4; ++i) {
                int idx = tid + 256 * i;
                int row = idx >> 3;
                int col = (idx & 7) * 8;
                aa[i] = *(const uint4*)(A + (size_t)(m0 + row) * DM + kb + col);
            }
            #pragma unroll
            for (int i = 0; i < 2; ++i) {
                int idx = tid + 256 * i;
                int rwb = idx >> 3;
                int cwb = (idx & 7) * 8;
                wbb[i] = *(const uint4*)(Wob + (size_t)(n0 + rwb) * DM + kb + cwb);
            }
        }

        bf16x8 af[2][2], bf[4][2];
        #pragma unroll
        for (int mt = 0; mt < 2; ++mt) {
            af[mt][0] = *(const bf16x8*)&As[cur][wave * 32 + mt * 16 + ln][g * 8];
            af[mt][1] = *(const bf16x8*)&As[cur][wave * 32 + mt * 16 + ln][32 + g * 8];
        }
        #pragma unroll
        for (int nt = 0; nt < 4; ++nt) {
            bf[nt][0] = *(const bf16x8*)&Bs[cur][nt * 16 + ln][g * 8];
            bf[nt][1] = *(const bf16x8*)&Bs[cur][nt * 16 + ln][32 + g * 8];
        }
        #pragma unroll
        for (int mt = 0; mt < 2; ++mt)
            #pragma unroll
            for (int nt = 0; nt < 4; ++nt) {
                acc[mt][nt] = mfma32(af[mt][0], bf[nt][0], acc[mt][nt]);
                acc[mt][nt] = mfma32(af[mt][1], bf[nt][1], acc[mt][nt]);
            }

        if (kt < 7) {
            int nxt = 1 - cur;
            #pragma unroll
            for (int i = 0; i < 4; ++i) {
                int idx = tid + 256 * i;
                int row = idx >> 3;
                int col = (idx & 7) * 8;
                *(uint4*)&As[nxt][row][col] = aa[i];
            }
            #pragma unroll
            for (int i = 0; i < 2; ++i) {
                int idx = tid + 256 * i;
                int rwb = idx >> 3;
                int cwb = (idx & 7) * 8;
                *(uint4*)&Bs[nxt][rwb][cwb] = wbb[i];
            }
        }
    }

    #pragma unroll
    for (int nt = 0; nt < 4; ++nt) {
        int n = n0 + nt * 16 + ln;
        float bias_n = bo[n];
        #pragma unroll
        for (int mt = 0; mt < 2; ++mt)
            #pragma unroll
            for (int r = 0; r < 4; ++r) {
                int m = m0 + wave * 32 + mt * 16 + g * 4 + r;
                out[(size_t)m * DM + n] = acc[mt][nt][r] + bias_n;
            }
    }
}

// ---------------------------------------------------------------------------
extern "C" void kernel_launch(void* const* d_in, const int* in_sizes, int n_in,
                              void* d_out, int out_size, void* d_ws, size_t ws_size,
                              hipStream_t stream) {
    (void)in_sizes; (void)n_in; (void)out_size; (void)ws_size;

    const float* query = (const float*)d_in[0];
    const float* key   = (const float*)d_in[1];
    const float* value = (const float*)d_in[2];
    const int*   mask  = (const int*)d_in[3];
    const float* Wq = (const float*)d_in[4];
    const float* bq = (const float*)d_in[5];
    const float* Wk = (const float*)d_in[6];
    const float* bk = (const float*)d_in[7];
    const float* Wv = (const float*)d_in[8];
    const float* bv = (const float*)d_in[9];
    const float* Wo = (const float*)d_in[10];
    const float* bo = (const float*)d_in[11];
    float* out = (float*)d_out;

    // ws layout (u16 elems): qws | kws | vws | ows | Opart(NSPLIT planes) |
    //                        lpart(f32) | wbf (4x 512x512 bf16)
    // xbf ALIASES Opart's first 3 planes: cvt_all writes it, proj_qkv reads
    // it, and only afterwards does flash overwrite Opart (stream-serial).
    const size_t PLANE = (size_t)NB * H * LSEQ * DK;   // 4,194,304
    u16* qws   = (u16*)d_ws;
    u16* kws   = qws + PLANE;
    u16* vws   = kws + PLANE;
    u16* ows   = vws + PLANE;
    u16* Opart = ows + PLANE;
    float* lpart = (float*)(Opart + (size_t)NSPLIT * PLANE);
    u16* wbf   = (u16*)(lpart + (size_t)NSPLIT * NB * H * LSEQ);
    u16* xbf   = Opart;   // 3 planes, dead until flash runs

    dim3 blk(256);
    cvt_all<<<dim3(2048, 7), blk, 0, stream>>>(Wq, Wk, Wv, Wo, query, key, value,
                                               wbf, xbf);
    proj_qkv<<<dim3(64, 4, 3), blk, 0, stream>>>(xbf, wbf, bq, bk, bv, mask,
                                                 qws, kws, vws);
    flash<<<dim3(32 * NSPLIT, H, NB), blk, 0, stream>>>(qws, kws, vws, mask, Opart, lpart);
    reduce_split<<<dim3(2048), blk, 0, stream>>>(Opart, lpart, ows);
    proj_out<<<dim3(64, 8, 1), blk, 0, stream>>>(ows, wbf + 3 * (size_t)DM * DM, bo, out);
}